// Round 1
// baseline (1019.514 us; speedup 1.0000x reference)
//
#include <hip/hip_runtime.h>

typedef unsigned short u16;
typedef __attribute__((ext_vector_type(8))) short s8v;
typedef __attribute__((ext_vector_type(8))) __bf16 bf8;
typedef __attribute__((ext_vector_type(4))) float f4v;

#define GLB(p) ((const __attribute__((address_space(1))) void*)(p))
#define LDS(p) ((__attribute__((address_space(3))) void*)(p))

static __device__ __forceinline__ float b2f(u16 u) {
    union { unsigned int i; float f; } v; v.i = ((unsigned int)u) << 16; return v.f;
}
static __device__ __forceinline__ u16 f2b(float f) {
    union { float f; unsigned int i; } v; v.f = f;
    v.i += 0x7fffu + ((v.i >> 16) & 1u);   // RNE
    return (u16)(v.i >> 16);
}

// ---------------- f32 -> bf16 convert, 4 elems/thread ----------------
__global__ __launch_bounds__(256) void k_conv(const float* __restrict__ in,
                                              u16* __restrict__ out, int n4) {
    int i = blockIdx.x * 256 + threadIdx.x;
    if (i >= n4) return;
    float4 v = ((const float4*)in)[i];
    union { u16 u[4]; unsigned long long ll; } o;
    o.u[0] = f2b(v.x); o.u[1] = f2b(v.y); o.u[2] = f2b(v.z); o.u[3] = f2b(v.w);
    ((unsigned long long*)out)[i] = o.ll;
}

// ---------------- C = A(MxK) * B(NxK)^T, 128x128 tile, BK=32 ----------------
// MODE 0: scatter bf16 into Q/K/V head-major [b][h][t][128]
// MODE 1: write f32 row-major C (M x N)
template<int MODE>
__global__ __launch_bounds__(256) void k_gemm_bt(
    const u16* __restrict__ A, const u16* __restrict__ B,
    int K, int N,
    u16* __restrict__ Qb, u16* __restrict__ Kb, u16* __restrict__ Vb,
    float* __restrict__ Cf)
{
    __shared__ __align__(16) u16 As[128 * 32];
    __shared__ __align__(16) u16 Bs[128 * 32];
    const int tid = threadIdx.x;
    const int lane = tid & 63;
    const int wid = tid >> 6;
    const int wr = wid >> 1, wc = wid & 1;         // 2x2 wave grid, 64x64 each
    const long arow0 = (long)blockIdx.y * 128;
    const long brow0 = (long)blockIdx.x * 128;
    const int la = lane & 15, lb = lane >> 4;

    f4v acc[4][4];
#pragma unroll
    for (int m = 0; m < 4; m++)
#pragma unroll
        for (int n = 0; n < 4; n++) acc[m][n] = (f4v){0.f, 0.f, 0.f, 0.f};

    const u16* Ag = A + (arow0 + (tid >> 2)) * (long)K + (tid & 3) * 8;
    const u16* Bg = B + (brow0 + (tid >> 2)) * (long)K + (tid & 3) * 8;
    const int aoff = (wr * 64 + la) * 32 + lb * 8;
    const int boff = (wc * 64 + la) * 32 + lb * 8;

    const int kiters = K >> 5;
    for (int kt = 0; kt < kiters; ++kt) {
        __syncthreads();
        const u16* ag = Ag + kt * 32;
        const u16* bg = Bg + kt * 32;
        __builtin_amdgcn_global_load_lds(GLB(ag),                LDS(As + tid * 8),        16, 0, 0);
        __builtin_amdgcn_global_load_lds(GLB(ag + 64 * (long)K), LDS(As + 2048 + tid * 8), 16, 0, 0);
        __builtin_amdgcn_global_load_lds(GLB(bg),                LDS(Bs + tid * 8),        16, 0, 0);
        __builtin_amdgcn_global_load_lds(GLB(bg + 64 * (long)K), LDS(Bs + 2048 + tid * 8), 16, 0, 0);
        __syncthreads();
        bf8 af[4], bfv[4];
#pragma unroll
        for (int m = 0; m < 4; m++) af[m] = *(const bf8*)(As + aoff + m * 512);
#pragma unroll
        for (int n = 0; n < 4; n++) bfv[n] = *(const bf8*)(Bs + boff + n * 512);
#pragma unroll
        for (int m = 0; m < 4; m++)
#pragma unroll
            for (int n = 0; n < 4; n++)
                acc[m][n] = __builtin_amdgcn_mfma_f32_16x16x32_bf16(af[m], bfv[n], acc[m][n], 0, 0, 0);
    }

#pragma unroll
    for (int m = 0; m < 4; m++) {
#pragma unroll
        for (int n = 0; n < 4; n++) {
            const long grow0 = arow0 + wr * 64 + m * 16 + lb * 4;
            const int  gcol  = (int)brow0 + wc * 64 + n * 16 + la;
#pragma unroll
            for (int i = 0; i < 4; i++) {
                const float v = acc[m][n][i];
                const long r = grow0 + i;
                if (MODE == 0) {
                    const int part = gcol >> 11;           // 0=Q 1=K 2=V
                    const int rem  = gcol & 2047;
                    const int head = rem >> 7, d = rem & 127;
                    u16* dst = (part == 0) ? Qb : ((part == 1) ? Kb : Vb);
                    const long bh = (r >> 11) * 16 + head;
                    dst[((bh << 11) + (r & 2047)) * 128 + d] = f2b(v);
                } else {
                    Cf[r * (long)N + gcol] = v;
                }
            }
        }
    }
}

// ---------------- RoPE in place on Q and K (head-major) ----------------
__global__ __launch_bounds__(256) void k_rope(u16* __restrict__ Qb, u16* __restrict__ Kb,
                                              const int* __restrict__ pos) {
    const int idx = blockIdx.x * 256 + threadIdx.x;   // 2 * 64 * 2048 * 64 threads
    const int j  = idx & 63;
    const int t  = (idx >> 6) & 2047;
    const int bh = (idx >> 17) & 63;
    u16* P = (idx >> 23) ? Kb : Qb;
    const long off = ((((long)bh << 11) + t) << 7) + 2 * j;
    unsigned int raw = *(unsigned int*)(P + off);
    float x1 = b2f((u16)(raw & 0xffffu));
    float x2 = b2f((u16)(raw >> 16));
    float invf = exp2f((float)j * -0.20762050593046014f);  // 10000^(-j/64)
    float ang = (float)pos[t] * invf;
    float sn, cs;
    sincosf(ang, &sn, &cs);
    unsigned int o = (unsigned int)f2b(x1 * cs - x2 * sn)
                   | ((unsigned int)f2b(x1 * sn + x2 * cs) << 16);
    *(unsigned int*)(P + off) = o;
}

// ---------------- causal flash attention: 1 wave per (bh, 32-row q tile) ----------------
__global__ __launch_bounds__(64) void k_attn(const u16* __restrict__ Qb,
                                             const u16* __restrict__ Kb,
                                             const u16* __restrict__ Vb,
                                             u16* __restrict__ Ob)
{
    __shared__ __align__(16) u16 Pl[32 * 32];
    const int lane = threadIdx.x;
    const int la = lane & 15, lb = lane >> 4;
    const int qt = blockIdx.x, bh = blockIdx.y;
    const long base = (long)bh << 18;          // bh * 2048 * 128
    const int q0 = qt * 32;
    const float scale = 0.08838834764831845f;  // 1/sqrt(128)

    bf8 qf[2][4];
#pragma unroll
    for (int m = 0; m < 2; m++)
#pragma unroll
        for (int kb = 0; kb < 4; kb++)
            qf[m][kb] = *(const bf8*)(Qb + base + (long)(q0 + m * 16 + la) * 128 + kb * 32 + lb * 8);

    f4v o[2][8];
#pragma unroll
    for (int m = 0; m < 2; m++)
#pragma unroll
        for (int n = 0; n < 8; n++) o[m][n] = (f4v){0.f, 0.f, 0.f, 0.f};
    float mst[2][4], lst[2][4];
#pragma unroll
    for (int m = 0; m < 2; m++)
#pragma unroll
        for (int i = 0; i < 4; i++) { mst[m][i] = -1e30f; lst[m][i] = 0.f; }

    char* Pb = (char*)Pl;

    for (int jt = 0; jt <= qt; ++jt) {
        const int kv0 = jt * 32;
        f4v s[2][2];
        s[0][0] = s[0][1] = s[1][0] = s[1][1] = (f4v){0.f, 0.f, 0.f, 0.f};
#pragma unroll
        for (int n = 0; n < 2; n++) {
#pragma unroll
            for (int kb = 0; kb < 4; kb++) {
                bf8 kf = *(const bf8*)(Kb + base + (long)(kv0 + n * 16 + la) * 128 + kb * 32 + lb * 8);
                s[0][n] = __builtin_amdgcn_mfma_f32_16x16x32_bf16(qf[0][kb], kf, s[0][n], 0, 0, 0);
                s[1][n] = __builtin_amdgcn_mfma_f32_16x16x32_bf16(qf[1][kb], kf, s[1][n], 0, 0, 0);
            }
        }
        float p[2][2][4];
        const bool diag = (jt == qt);
#pragma unroll
        for (int m = 0; m < 2; m++)
#pragma unroll
            for (int n = 0; n < 2; n++)
#pragma unroll
                for (int i = 0; i < 4; i++) {
                    float v = s[m][n][i] * scale;
                    if (diag && (n * 16 + la) > (m * 16 + lb * 4 + i)) v = -1e30f;
                    p[m][n][i] = v;
                }
        float corr[2][4];
#pragma unroll
        for (int m = 0; m < 2; m++)
#pragma unroll
            for (int i = 0; i < 4; i++) {
                float r = fmaxf(p[m][0][i], p[m][1][i]);
                r = fmaxf(r, __shfl_xor(r, 1));
                r = fmaxf(r, __shfl_xor(r, 2));
                r = fmaxf(r, __shfl_xor(r, 4));
                r = fmaxf(r, __shfl_xor(r, 8));
                const float mnew = fmaxf(mst[m][i], r);
                const float c = __expf(mst[m][i] - mnew);
                mst[m][i] = mnew;
                corr[m][i] = c;
                float sum = 0.f;
#pragma unroll
                for (int n = 0; n < 2; n++) {
                    p[m][n][i] = __expf(p[m][n][i] - mnew);
                    sum += p[m][n][i];
                }
                sum += __shfl_xor(sum, 1);
                sum += __shfl_xor(sum, 2);
                sum += __shfl_xor(sum, 4);
                sum += __shfl_xor(sum, 8);
                lst[m][i] = lst[m][i] * c + sum;
            }
#pragma unroll
        for (int m = 0; m < 2; m++)
#pragma unroll
            for (int n = 0; n < 8; n++)
#pragma unroll
                for (int i = 0; i < 4; i++) o[m][n][i] *= corr[m][i];

        __syncthreads();   // protect Pl reuse
#pragma unroll
        for (int m = 0; m < 2; m++)
#pragma unroll
            for (int n = 0; n < 2; n++)
#pragma unroll
                for (int i = 0; i < 4; i++) {
                    const int row = m * 16 + lb * 4 + i;
                    const int colb = (n * 16 + la) * 2;
                    *(u16*)(Pb + row * 64 + (colb ^ ((row & 3) << 4))) = f2b(p[m][n][i]);
                }
        __syncthreads();
        bf8 pa[2];
#pragma unroll
        for (int am = 0; am < 2; am++) {
            const int row = am * 16 + la;
            pa[am] = *(const bf8*)(Pb + row * 64 + ((lb * 16) ^ ((row & 3) << 4)));
        }
        const u16* Vg = Vb + base + (long)(kv0 + lb * 8) * 128;
#pragma unroll
        for (int nO = 0; nO < 8; nO++) {
            const int d = nO * 16 + la;
            s8v vt;
#pragma unroll
            for (int i2 = 0; i2 < 8; i2++) vt[i2] = (short)Vg[i2 * 128 + d];
            bf8 vf = __builtin_bit_cast(bf8, vt);
            o[0][nO] = __builtin_amdgcn_mfma_f32_16x16x32_bf16(pa[0], vf, o[0][nO], 0, 0, 0);
            o[1][nO] = __builtin_amdgcn_mfma_f32_16x16x32_bf16(pa[1], vf, o[1][nO], 0, 0, 0);
        }
    }

    const int b = bh >> 4, h = bh & 15;
#pragma unroll
    for (int m = 0; m < 2; m++)
#pragma unroll
        for (int nO = 0; nO < 8; nO++)
#pragma unroll
            for (int i = 0; i < 4; i++) {
                const int row = q0 + m * 16 + lb * 4 + i;
                const int d = nO * 16 + la;
                Ob[((long)(b * 2048 + row) << 11) + h * 128 + d] = f2b(o[m][nO][i] / lst[m][i]);
            }
}

extern "C" void kernel_launch(void* const* d_in, const int* in_sizes, int n_in,
                              void* d_out, int out_size, void* d_ws, size_t ws_size,
                              hipStream_t stream)
{
    const float* X    = (const float*)d_in[0];
    const int*   pos  = (const int*)d_in[1];
    const float* Wqkv = (const float*)d_in[2];
    const float* Wo   = (const float*)d_in[3];
    float* out = (float*)d_out;

    char* ws = (char*)d_ws;
    u16* Xb    = (u16*)(ws + 0);          // 8192x2048 bf16   (32 MiB)
    u16* Wqkvb = (u16*)(ws + 33554432);   // 6144x2048 bf16   (24 MiB)
    u16* Wob   = (u16*)(ws + 58720256);   // 2048x2048 bf16   ( 8 MiB)
    u16* Qb    = (u16*)(ws + 67108864);   // [b][h][t][128] bf16 (32 MiB)
    u16* Kb    = (u16*)(ws + 100663296);
    u16* Vb    = (u16*)(ws + 134217728);
    u16* Ob    = (u16*)(ws + 167772160);  // [b][t][2048] bf16

    k_conv<<<16384, 256, 0, stream>>>(X, Xb, 4194304);
    k_conv<<<12288, 256, 0, stream>>>(Wqkv, Wqkvb, 3145728);
    k_conv<<<4096, 256, 0, stream>>>(Wo, Wob, 1048576);
    k_gemm_bt<0><<<dim3(48, 64), 256, 0, stream>>>(Xb, Wqkvb, 2048, 6144, Qb, Kb, Vb, nullptr);
    k_rope<<<65536, 256, 0, stream>>>(Qb, Kb, pos);
    k_attn<<<dim3(64, 64), 64, 0, stream>>>(Qb, Kb, Vb, Ob);
    k_gemm_bt<1><<<dim3(16, 64), 256, 0, stream>>>(Ob, Wob, 2048, 2048, nullptr, nullptr, nullptr, out);
}